// Round 10
// baseline (278.205 us; speedup 1.0000x reference)
//
#include <hip/hip_runtime.h>
#include <cfloat>
#include <climits>

// Problem constants: x (16,2048,256) fp32 -> N=32768 rows; weight (4096,256) fp32.
constexpr int E  = 256;    // quantizing_dim
constexpr int Qn = 4096;   // num_quantizing
constexpr float WSCALE = 4096.0f;   // 2^12 exact pow2 (keeps f16 products well-scaled)

// Round 10: column-quarter blocks. Each block loops 8 column-tiles, keeping a
// per-lane running top-3 of packed keys (bits(acc)&~0xFFF | idx) in registers;
// ONE LDS merge per block -> per-(row,quarter) top-4 (2 MB total, was 16.8 MB
// with 32 merges/row-band). Finalize: 16 uniform candidates, shuffle-free
// in-register top-4, then the r1-validated exact fp32 rescore + lex tie-break.

typedef _Float16 half8  __attribute__((ext_vector_type(8)));
typedef _Float16 half4v __attribute__((ext_vector_type(4)));
typedef float    f32x16 __attribute__((ext_vector_type(16)));

#define GAS __attribute__((address_space(1)))
#define LAS __attribute__((address_space(3)))

#define NEG_INF __int_as_float(0xFF800000)

__device__ inline bool lexlt(float a, int ai, float b, int bi) {
    return a < b || (a == b && ai < bi);
}

// ---------------------------------------------------------------------------
// Prep: one 64-lane wave per row (x and w). Emits f16 operand + sumsq.
// ---------------------------------------------------------------------------
__global__ __launch_bounds__(256) void prep_kernel(
    const float* __restrict__ x, const float* __restrict__ w,
    _Float16* __restrict__ A16, _Float16* __restrict__ B16,
    float* __restrict__ x2, float* __restrict__ w2, int nxblocks)
{
    int blk  = blockIdx.x;
    int sub  = threadIdx.x >> 6;
    int lane = threadIdx.x & 63;
    bool isX = blk < nxblocks;
    int row  = (isX ? blk : blk - nxblocks) * 4 + sub;

    const float* src = isX ? x : w;
    float4 v = *(const float4*)(src + (size_t)row * E + lane * 4);

    float s = v.x * v.x + v.y * v.y + v.z * v.z + v.w * v.w;   // UNSCALED sumsq
    #pragma unroll
    for (int off = 32; off; off >>= 1) s += __shfl_xor(s, off);
    if (lane == 0) (isX ? x2 : w2)[row] = s;

    float sc = isX ? 1.0f : WSCALE;                            // exact pow2
    half4v h = { (_Float16)(v.x * sc), (_Float16)(v.y * sc),
                 (_Float16)(v.z * sc), (_Float16)(v.w * sc) };
    _Float16* dst16 = (isX ? A16 : B16) + (size_t)row * 256;
    *(half4v*)(dst16 + lane * 4) = h;
}

// ---------------------------------------------------------------------------
// Main MFMA kernel: grid (N/128, 4). Block = 128 x-rows x 1024 codewords
// (loops 8 column-tiles of 128). Per-lane running top-3 packed keys; one
// LDS merge per block -> per-(row,quarter) top-4 float4.
// ---------------------------------------------------------------------------
__device__ inline void ins4max(float K[4], float k) {
    #pragma unroll
    for (int t = 0; t < 4; ++t) {            // keep K descending
        float mx = fmaxf(K[t], k);
        k = fminf(K[t], k);
        K[t] = mx;
    }
}

union SmemU {
    struct { _Float16 W[128 * 64]; _Float16 X[128 * 64]; } st;  // 32 KB staging
    float mS[128 * 12];                                          // 6 KB (post-loop)
};

__global__ __launch_bounds__(256, 4) void vq_mfma_kernel(
    const _Float16* __restrict__ A16,      // (N, 256)  xh
    const _Float16* __restrict__ B16,      // (Qn, 256) wh_s
    float4* __restrict__ top4)             // (N, 4) packed {k0..k3} per quarter
{
    __shared__ SmemU sm;

    const int tid  = threadIdx.x;
    const int w    = tid >> 6;
    const int lane = tid & 63;
    const int l31  = lane & 31;
    const int lh   = lane >> 5;          // k-half select
    const int rb   = blockIdx.x;         // row band (128 x-rows)
    const int qq   = blockIdx.y;         // column quarter (1024 codewords)

    const int wr = (w & 1) * 64;         // wave's x-row quadrant base
    const int wc = (w >> 1) * 64;        // wave's codeword quadrant base

    const _Float16* Ab16 = A16 + (size_t)rb * 128 * 256;

    const int srow = lane >> 3;   // staging: row-in-8 group
    const int schk = lane & 7;    // staging: dest 16B chunk

    // per-lane running top-3 packed keys, per g (x-row sub-tile)
    float t1[2] = { NEG_INF, NEG_INF };
    float t2[2] = { NEG_INF, NEG_INF };
    float t3[2] = { NEG_INF, NEG_INF };

    for (int cn = 0; cn < 8; ++cn) {
        const int cg = qq * 8 + cn;
        const _Float16* Bb16 = B16 + (size_t)cg * 128 * 256;

        f32x16 acc[2][2];
        #pragma unroll
        for (int f = 0; f < 2; ++f)
            #pragma unroll
            for (int g = 0; g < 2; ++g)
                #pragma unroll
                for (int r = 0; r < 16; ++r) acc[f][g][r] = 0.0f;

        for (int kt = 0; kt < 4; ++kt) {
            __syncthreads();
            #pragma unroll
            for (int inst = 0; inst < 4; ++inst) {
                int drow = w * 32 + inst * 8 + srow;          // 0..127
                int gchk = schk ^ (drow & 7);                 // source chunk swizzle
                const _Float16* gW = Bb16 + (size_t)drow * 256 + kt * 64 + gchk * 8;
                const _Float16* gX = Ab16 + (size_t)drow * 256 + kt * 64 + gchk * 8;
                __builtin_amdgcn_global_load_lds((const GAS void*)gW,
                    (LAS void*)(sm.st.W + w * 2048 + inst * 512), 16, 0, 0);
                __builtin_amdgcn_global_load_lds((const GAS void*)gX,
                    (LAS void*)(sm.st.X + w * 2048 + inst * 512), 16, 0, 0);
            }
            __syncthreads();

            #pragma unroll
            for (int s = 0; s < 4; ++s) {
                const int kc = 2 * s + lh;
                half8 wf[2], xf[2];
                #pragma unroll
                for (int f = 0; f < 2; ++f) {
                    int fr = wc + 32 * f + l31;
                    wf[f] = *(const half8*)(sm.st.W + fr * 64 + ((kc ^ (fr & 7)) << 3));
                    int xr = wr + 32 * f + l31;
                    xf[f] = *(const half8*)(sm.st.X + xr * 64 + ((kc ^ (xr & 7)) << 3));
                }
                #pragma unroll
                for (int f = 0; f < 2; ++f)
                    #pragma unroll
                    for (int g = 0; g < 2; ++g)
                        acc[f][g] = __builtin_amdgcn_mfma_f32_32x32x16_f16(
                            wf[f], xf[g], acc[f][g], 0, 0, 0);
            }
        }

        // ---- update running top-3 with this tile's 64 packed keys ----
        #pragma unroll
        for (int f = 0; f < 2; ++f)
            #pragma unroll
            for (int r = 0; r < 16; ++r) {
                int m  = (r & 3) + 8 * (r >> 2) + 4 * lh;     // C-row mapping (32x32)
                int qg = cg * 128 + wc + 32 * f + m;          // global codeword id
                #pragma unroll
                for (int g = 0; g < 2; ++g) {
                    float pk = __int_as_float(
                        (__float_as_int(acc[f][g][r]) & 0xFFFFF000) | qg);
                    float mn = fminf(t2[g], pk);              // uses OLD t2
                    t3[g] = fmaxf(t3[g], mn);
                    t2[g] = __builtin_amdgcn_fmed3f(t1[g], t2[g], pk);  // OLD t1,t2
                    t1[g] = fmaxf(t1[g], pk);
                }
            }
    }

    __syncthreads();   // all staging reads done -> overlay merge area

    #pragma unroll
    for (int g = 0; g < 2; ++g) {
        int rrow = wr + 32 * g + l31;
        int src  = (w >> 1) * 2 + lh;            // 0..3
        sm.mS[rrow * 12 + src * 3 + 0] = t1[g];
        sm.mS[rrow * 12 + src * 3 + 1] = t2[g];
        sm.mS[rrow * 12 + src * 3 + 2] = t3[g];
    }
    __syncthreads();

    if (tid < 128) {
        float K[4] = { NEG_INF, NEG_INF, NEG_INF, NEG_INF };
        #pragma unroll
        for (int s = 0; s < 12; ++s) ins4max(K, sm.mS[tid * 12 + s]);
        top4[(size_t)(rb * 128 + tid) * 4 + qq] =
            make_float4(K[0], K[1], K[2], K[3]);
    }
}

// ---------------------------------------------------------------------------
// Finalize: per row, 4 quarters x top-4 = 16 uniform candidates -> in-register
// top-4 (no shuffles, no divergence) -> exact fp32 rescore (reference formula
// + first-index tie-break), write outputs. One 64-lane wave per row.
// ---------------------------------------------------------------------------
__global__ __launch_bounds__(256) void finalize_kernel(
    const float4* __restrict__ top4, const float* __restrict__ x,
    const float* __restrict__ w, const float* __restrict__ x2,
    const float* __restrict__ w2, float* __restrict__ qdata,
    float* __restrict__ qidx)
{
    int row  = blockIdx.x * 4 + (threadIdx.x >> 6);
    int lane = threadIdx.x & 63;

    // wave-uniform candidate loads (scalar-broadcast friendly)
    float K[4] = { NEG_INF, NEG_INF, NEG_INF, NEG_INF };
    #pragma unroll
    for (int j = 0; j < 4; ++j) {
        float4 c = top4[(size_t)row * 4 + j];
        ins4max(K, c.x); ins4max(K, c.y); ins4max(K, c.z); ins4max(K, c.w);
    }
    int chosen[4];
    #pragma unroll
    for (int j = 0; j < 4; ++j) chosen[j] = __float_as_int(K[j]) & 0xFFF;

    // exact fp32 rescore of the 4 survivors (round-1-validated formula)
    float4 xv = *(const float4*)(x + (size_t)row * E + lane * 4);
    float d[4];
    #pragma unroll
    for (int j = 0; j < 4; ++j) {
        float4 wv = *(const float4*)(w + (size_t)chosen[j] * E + lane * 4);
        d[j] = xv.x * wv.x + xv.y * wv.y + xv.z * wv.z + xv.w * wv.w;
    }
    #pragma unroll
    for (int off = 32; off; off >>= 1) {
        #pragma unroll
        for (int j = 0; j < 4; ++j) d[j] += __shfl_xor(d[j], off);
    }

    float X2 = x2[row];
    float bs = FLT_MAX; int win = INT_MAX;
    #pragma unroll
    for (int j = 0; j < 4; ++j) {
        float s = (X2 - 2.0f * d[j]) + w2[chosen[j]];
        if (lexlt(s, chosen[j], bs, win)) { bs = s; win = chosen[j]; }
    }

    if (lane == 0) qidx[row] = (float)win;
    *(float4*)(qdata + (size_t)row * E + lane * 4) =
        *(const float4*)(w + (size_t)win * E + lane * 4);
}

// ---------------------------------------------------------------------------
// Round-1 fp32 fallback (only if ws_size too small). Passed absmax 0.
// ---------------------------------------------------------------------------
constexpr int FBM = 64, FBN = 128, FBK = 64, FPAD = 4, FTH = 256;

__global__ __launch_bounds__(64) void row_sumsq_kernel(const float* __restrict__ src,
                                                       float* __restrict__ dst) {
    int row = blockIdx.x, lane = threadIdx.x;
    float4 v = ((const float4*)(src + (size_t)row * E))[lane];
    float s = v.x * v.x + v.y * v.y + v.z * v.z + v.w * v.w;
    #pragma unroll
    for (int off = 32; off > 0; off >>= 1) s += __shfl_down(s, off);
    if (lane == 0) dst[row] = s;
}

__global__ __launch_bounds__(FTH) void vq_fallback_kernel(
    const float* __restrict__ x, const float* __restrict__ w,
    const float* __restrict__ x2, const float* __restrict__ w2,
    float* __restrict__ qdata, float* __restrict__ qidx)
{
    __shared__ float xs[FBM][FBK + FPAD];
    __shared__ float ws[FBN][FBK + FPAD];
    __shared__ float redS[FBM][16];
    __shared__ int   redC[FBM][16];
    __shared__ int   bestC[FBM];

    const int tid = threadIdx.x, tr = tid >> 4, tc = tid & 15;
    const int r0 = blockIdx.x * FBM;
    float best[4]; int bidx[4];
    #pragma unroll
    for (int i = 0; i < 4; ++i) { best[i] = FLT_MAX; bidx[i] = 0x7FFFFFFF; }
    float x2r[4];
    #pragma unroll
    for (int i = 0; i < 4; ++i) x2r[i] = x2[r0 + tr + 16 * i];

    for (int qt = 0; qt < Qn / FBN; ++qt) {
        const int c0 = qt * FBN;
        float acc[4][8];
        #pragma unroll
        for (int i = 0; i < 4; ++i)
            #pragma unroll
            for (int j = 0; j < 8; ++j) acc[i][j] = 0.f;
        for (int kt = 0; kt < E / FBK; ++kt) {
            __syncthreads();
            const int kk = (tid & 15) * 4, rr = tid >> 4;
            #pragma unroll
            for (int m = 0; m < 4; ++m)
                *(float4*)&xs[m * 16 + rr][kk] =
                    *(const float4*)(x + (size_t)(r0 + m * 16 + rr) * E + kt * FBK + kk);
            #pragma unroll
            for (int m = 0; m < 8; ++m)
                *(float4*)&ws[m * 16 + rr][kk] =
                    *(const float4*)(w + (size_t)(c0 + m * 16 + rr) * E + kt * FBK + kk);
            __syncthreads();
            #pragma unroll
            for (int k4 = 0; k4 < FBK / 4; ++k4) {
                float4 a[4], bb[8];
                #pragma unroll
                for (int i = 0; i < 4; ++i) a[i] = *(const float4*)&xs[tr + 16 * i][k4 * 4];
                #pragma unroll
                for (int j = 0; j < 8; ++j) bb[j] = *(const float4*)&ws[tc + 16 * j][k4 * 4];
                #pragma unroll
                for (int i = 0; i < 4; ++i)
                    #pragma unroll
                    for (int j = 0; j < 8; ++j) {
                        acc[i][j] += a[i].x * bb[j].x; acc[i][j] += a[i].y * bb[j].y;
                        acc[i][j] += a[i].z * bb[j].z; acc[i][j] += a[i].w * bb[j].w;
                    }
            }
        }
        #pragma unroll
        for (int i = 0; i < 4; ++i)
            #pragma unroll
            for (int j = 0; j < 8; ++j) {
                int c = c0 + tc + 16 * j;
                float s = (x2r[i] - 2.0f * acc[i][j]) + w2[c];
                if (s < best[i]) { best[i] = s; bidx[i] = c; }
            }
    }
    #pragma unroll
    for (int i = 0; i < 4; ++i) { redS[tr + 16 * i][tc] = best[i]; redC[tr + 16 * i][tc] = bidx[i]; }
    __syncthreads();
    if (tid < FBM) {
        float bs = FLT_MAX; int bc = 0x7FFFFFFF;
        #pragma unroll
        for (int t = 0; t < 16; ++t) {
            float s = redS[tid][t]; int c = redC[tid][t];
            if (s < bs || (s == bs && c < bc)) { bs = s; bc = c; }
        }
        qidx[r0 + tid] = (float)bc; bestC[tid] = bc;
    }
    __syncthreads();
    for (int it = 0; it < FBM / 4; ++it) {
        int row = it * 4 + (tid >> 6), c = bestC[row], kk = (tid & 63) * 4;
        *(float4*)(qdata + (size_t)(r0 + row) * E + kk) = *(const float4*)(w + (size_t)c * E + kk);
    }
}

// ---------------------------------------------------------------------------
extern "C" void kernel_launch(void* const* d_in, const int* in_sizes, int n_in,
                              void* d_out, int out_size, void* d_ws, size_t ws_size,
                              hipStream_t stream) {
    const float* x = (const float*)d_in[0];
    const float* w = (const float*)d_in[1];
    const int N = in_sizes[0] / E;                      // 32768

    float* qdata = (float*)d_out;
    float* qidx  = (float*)d_out + (size_t)N * E;

    size_t off = 0;
    auto carve = [&](size_t bytes) { size_t p = off; off += (bytes + 255) & ~(size_t)255; return p; };
    size_t oA16 = carve((size_t)N  * 256 * sizeof(_Float16));     // 16.8 MB
    size_t oB16 = carve((size_t)Qn * 256 * sizeof(_Float16));     //  2.1 MB
    size_t ox2  = carve((size_t)N * sizeof(float));
    size_t ow2  = carve((size_t)Qn * sizeof(float));
    size_t oT   = carve((size_t)N * 4 * sizeof(float4));          //  2.1 MB

    if (ws_size >= off && (N % 128) == 0) {
        char* ws = (char*)d_ws;
        _Float16* A16 = (_Float16*)(ws + oA16);
        _Float16* B16 = (_Float16*)(ws + oB16);
        float* x2    = (float*)(ws + ox2);
        float* w2    = (float*)(ws + ow2);
        float4* top4 = (float4*)(ws + oT);

        prep_kernel<<<N / 4 + Qn / 4, 256, 0, stream>>>(x, w, A16, B16, x2, w2, N / 4);
        vq_mfma_kernel<<<dim3(N / 128, 4), 256, 0, stream>>>(A16, B16, top4);
        finalize_kernel<<<N / 4, 256, 0, stream>>>(top4, x, w, x2, w2, qdata, qidx);
    } else {
        float* x2 = (float*)d_ws;
        float* w2 = x2 + N;
        row_sumsq_kernel<<<N, 64, 0, stream>>>(x, x2);
        row_sumsq_kernel<<<Qn, 64, 0, stream>>>(w, w2);
        vq_fallback_kernel<<<N / FBM, FTH, 0, stream>>>(x, w, x2, w2, qdata, qidx);
    }
}

// Round 11
// 195.732 us; speedup vs baseline: 1.4214x; 1.4214x over previous
//
#include <hip/hip_runtime.h>
#include <cfloat>
#include <climits>

// Problem constants: x (16,2048,256) fp32 -> N=32768 rows; weight (4096,256) fp32.
constexpr int E  = 256;    // quantizing_dim
constexpr int Qn = 4096;   // num_quantizing
constexpr float WSCALE = 4096.0f;   // 2^12 exact pow2 (keeps f16 products well-scaled)

// Round 11 = round 9 (best validated: 201.5 us) reverted after round-10's
// grid-collapse regression (fewer/longer blocks halved MfmaUtil — this K-loop
// needs many short blocks for barrier-stall hiding), with one cleanup:
// x2 computed inside finalize from xv (same butterfly order -> bit-identical),
// removing prep's x-row reduction and the x2 buffer.

typedef _Float16 half8  __attribute__((ext_vector_type(8)));
typedef _Float16 half4v __attribute__((ext_vector_type(4)));
typedef float    f32x16 __attribute__((ext_vector_type(16)));

#define GAS __attribute__((address_space(1)))
#define LAS __attribute__((address_space(3)))

#define NEG_INF __int_as_float(0xFF800000)

__device__ inline bool lexlt(float a, int ai, float b, int bi) {
    return a < b || (a == b && ai < bi);
}

// ---------------------------------------------------------------------------
// Prep: one 64-lane wave per row (x and w). Emits f16 operand; sumsq only for w.
// ---------------------------------------------------------------------------
__global__ __launch_bounds__(256) void prep_kernel(
    const float* __restrict__ x, const float* __restrict__ w,
    _Float16* __restrict__ A16, _Float16* __restrict__ B16,
    float* __restrict__ w2, int nxblocks)
{
    int blk  = blockIdx.x;
    int sub  = threadIdx.x >> 6;
    int lane = threadIdx.x & 63;
    bool isX = blk < nxblocks;
    int row  = (isX ? blk : blk - nxblocks) * 4 + sub;

    const float* src = isX ? x : w;
    float4 v = *(const float4*)(src + (size_t)row * E + lane * 4);

    if (!isX) {
        float s = v.x * v.x + v.y * v.y + v.z * v.z + v.w * v.w;   // UNSCALED sumsq
        #pragma unroll
        for (int off = 32; off; off >>= 1) s += __shfl_xor(s, off);
        if (lane == 0) w2[row] = s;
    }

    float sc = isX ? 1.0f : WSCALE;                            // exact pow2
    half4v h = { (_Float16)(v.x * sc), (_Float16)(v.y * sc),
                 (_Float16)(v.z * sc), (_Float16)(v.w * sc) };
    _Float16* dst16 = (isX ? A16 : B16) + (size_t)row * 256;
    *(half4v*)(dst16 + lane * 4) = h;
}

// ---------------------------------------------------------------------------
// Main MFMA kernel: block = 128 x-rows x 128 codewords, grid (N/128, Qn/128).
// K=256 f16 GEMM; epilogue keeps per-lane packed top-2 (maximize dot), merged
// to per-(row,cg) top-4 packed floats (one float4). Identical to round 9.
// ---------------------------------------------------------------------------
__device__ inline void ins4max(float K[4], float k) {
    #pragma unroll
    for (int t = 0; t < 4; ++t) {            // keep K descending
        float mx = fmaxf(K[t], k);
        k = fminf(K[t], k);
        K[t] = mx;
    }
}

union SmemU {
    struct { _Float16 W[128 * 64]; _Float16 X[128 * 64]; } st;  // 32 KB staging
    float2 mergeS[128 * 4];                                      // 4 KB (post-loop)
};

__global__ __launch_bounds__(256, 4) void vq_mfma_kernel(
    const _Float16* __restrict__ A16,      // (N, 256)  xh
    const _Float16* __restrict__ B16,      // (Qn, 256) wh_s
    float4* __restrict__ top4)             // (N, 32) packed {k0,k1,k2,k3} desc
{
    __shared__ SmemU sm;

    const int tid  = threadIdx.x;
    const int w    = tid >> 6;
    const int lane = tid & 63;
    const int l31  = lane & 31;
    const int lh   = lane >> 5;          // k-half select
    const int rb   = blockIdx.x;         // row band (128 x-rows)
    const int cg   = blockIdx.y;         // col group (128 codewords)

    const int wr = (w & 1) * 64;         // wave's x-row quadrant base
    const int wc = (w >> 1) * 64;        // wave's codeword quadrant base

    f32x16 acc[2][2];
    #pragma unroll
    for (int f = 0; f < 2; ++f)
        #pragma unroll
        for (int g = 0; g < 2; ++g)
            #pragma unroll
            for (int r = 0; r < 16; ++r) acc[f][g][r] = 0.0f;

    const _Float16* Ab16 = A16 + (size_t)rb * 128 * 256;
    const _Float16* Bb16 = B16 + (size_t)cg * 128 * 256;

    const int srow = lane >> 3;   // staging: row-in-8 group
    const int schk = lane & 7;    // staging: dest 16B chunk

    for (int kt = 0; kt < 4; ++kt) {
        __syncthreads();
        #pragma unroll
        for (int inst = 0; inst < 4; ++inst) {
            int drow = w * 32 + inst * 8 + srow;          // 0..127
            int gchk = schk ^ (drow & 7);                 // source chunk swizzle
            const _Float16* gW = Bb16 + (size_t)drow * 256 + kt * 64 + gchk * 8;
            const _Float16* gX = Ab16 + (size_t)drow * 256 + kt * 64 + gchk * 8;
            __builtin_amdgcn_global_load_lds((const GAS void*)gW,
                (LAS void*)(sm.st.W + w * 2048 + inst * 512), 16, 0, 0);
            __builtin_amdgcn_global_load_lds((const GAS void*)gX,
                (LAS void*)(sm.st.X + w * 2048 + inst * 512), 16, 0, 0);
        }
        __syncthreads();

        #pragma unroll
        for (int s = 0; s < 4; ++s) {
            const int kc = 2 * s + lh;
            half8 wf[2], xf[2];
            #pragma unroll
            for (int f = 0; f < 2; ++f) {
                int fr = wc + 32 * f + l31;
                wf[f] = *(const half8*)(sm.st.W + fr * 64 + ((kc ^ (fr & 7)) << 3));
                int xr = wr + 32 * f + l31;
                xf[f] = *(const half8*)(sm.st.X + xr * 64 + ((kc ^ (xr & 7)) << 3));
            }
            #pragma unroll
            for (int f = 0; f < 2; ++f)
                #pragma unroll
                for (int g = 0; g < 2; ++g)
                    acc[f][g] = __builtin_amdgcn_mfma_f32_32x32x16_f16(
                        wf[f], xf[g], acc[f][g], 0, 0, 0);
        }
    }

    // ---- epilogue: packed key = (bits(acc) & ~0xFFF) | qg; maximize ----
    float t1[2] = { NEG_INF, NEG_INF }, t2[2] = { NEG_INF, NEG_INF };

    #pragma unroll
    for (int f = 0; f < 2; ++f)
        #pragma unroll
        for (int r = 0; r < 16; ++r) {
            int m  = (r & 3) + 8 * (r >> 2) + 4 * lh;     // C-row mapping (32x32)
            int qg = cg * 128 + wc + 32 * f + m;          // global codeword id
            #pragma unroll
            for (int g = 0; g < 2; ++g) {
                float pk = __int_as_float(
                    (__float_as_int(acc[f][g][r]) & 0xFFFFF000) | qg);
                t2[g] = __builtin_amdgcn_fmed3f(t1[g], t2[g], pk);
                t1[g] = fmaxf(t1[g], pk);
            }
        }

    __syncthreads();   // staging reads done -> overlay mergeS

    #pragma unroll
    for (int g = 0; g < 2; ++g) {
        int rrow = wr + 32 * g + l31;
        sm.mergeS[rrow * 4 + ((w >> 1) * 2 + lh)] = make_float2(t1[g], t2[g]);
    }
    __syncthreads();

    if (tid < 128) {
        float K[4] = { NEG_INF, NEG_INF, NEG_INF, NEG_INF };
        #pragma unroll
        for (int sl = 0; sl < 4; ++sl) {
            float2 a = sm.mergeS[tid * 4 + sl];
            ins4max(K, a.x);
            ins4max(K, a.y);
        }
        top4[(size_t)(rb * 128 + tid) * 32 + cg] =
            make_float4(K[0], K[1], K[2], K[3]);
    }
}

// ---------------------------------------------------------------------------
// Finalize: per row, 32 cg x top-4 packed candidates -> global top-4 by packed
// key (wave-max passes w/ bitwise invalidation) -> exact fp32 rescore
// (reference formula + first-index tie-break; X2 computed in-kernel with the
// same butterfly order as the validated prep reduction), write outputs.
// ---------------------------------------------------------------------------
__global__ __launch_bounds__(256) void finalize_kernel(
    const float4* __restrict__ top4, const float* __restrict__ x,
    const float* __restrict__ w, const float* __restrict__ w2,
    float* __restrict__ qdata, float* __restrict__ qidx)
{
    int row  = blockIdx.x * 4 + (threadIdx.x >> 6);
    int lane = threadIdx.x & 63;

    float cand[4];
    if (lane < 32) {
        float4 c4 = top4[(size_t)row * 32 + lane];
        cand[0] = c4.x; cand[1] = c4.y; cand[2] = c4.z; cand[3] = c4.w;
    } else {
        cand[0] = cand[1] = cand[2] = cand[3] = NEG_INF;
    }

    int chosen[4];
    #pragma unroll
    for (int p = 0; p < 4; ++p) {
        float cur = fmaxf(fmaxf(cand[0], cand[1]), fmaxf(cand[2], cand[3]));
        #pragma unroll
        for (int off = 32; off; off >>= 1)
            cur = fmaxf(cur, __shfl_xor(cur, off));
        int curb = __float_as_int(cur);
        chosen[p] = curb & 0xFFF;
        #pragma unroll
        for (int j = 0; j < 4; ++j)
            if (__float_as_int(cand[j]) == curb) cand[j] = NEG_INF;
    }

    // exact fp32 rescore of the 4 survivors (round-1-validated formula);
    // X2 via the same data layout + butterfly order as the old prep reduction.
    float4 xv = *(const float4*)(x + (size_t)row * E + lane * 4);
    float s2 = xv.x * xv.x + xv.y * xv.y + xv.z * xv.z + xv.w * xv.w;
    float d[4];
    #pragma unroll
    for (int j = 0; j < 4; ++j) {
        float4 wv = *(const float4*)(w + (size_t)chosen[j] * E + lane * 4);
        d[j] = xv.x * wv.x + xv.y * wv.y + xv.z * wv.z + xv.w * wv.w;
    }
    #pragma unroll
    for (int off = 32; off; off >>= 1) {
        s2 += __shfl_xor(s2, off);
        #pragma unroll
        for (int j = 0; j < 4; ++j) d[j] += __shfl_xor(d[j], off);
    }

    float bs = FLT_MAX; int win = INT_MAX;
    #pragma unroll
    for (int j = 0; j < 4; ++j) {
        float s = (s2 - 2.0f * d[j]) + w2[chosen[j]];
        if (lexlt(s, chosen[j], bs, win)) { bs = s; win = chosen[j]; }
    }

    if (lane == 0) qidx[row] = (float)win;
    *(float4*)(qdata + (size_t)row * E + lane * 4) =
        *(const float4*)(w + (size_t)win * E + lane * 4);
}

// ---------------------------------------------------------------------------
// Round-1 fp32 fallback (only if ws_size too small). Passed absmax 0.
// ---------------------------------------------------------------------------
constexpr int FBM = 64, FBN = 128, FBK = 64, FPAD = 4, FTH = 256;

__global__ __launch_bounds__(64) void row_sumsq_kernel(const float* __restrict__ src,
                                                       float* __restrict__ dst) {
    int row = blockIdx.x, lane = threadIdx.x;
    float4 v = ((const float4*)(src + (size_t)row * E))[lane];
    float s = v.x * v.x + v.y * v.y + v.z * v.z + v.w * v.w;
    #pragma unroll
    for (int off = 32; off > 0; off >>= 1) s += __shfl_down(s, off);
    if (lane == 0) dst[row] = s;
}

__global__ __launch_bounds__(FTH) void vq_fallback_kernel(
    const float* __restrict__ x, const float* __restrict__ w,
    const float* __restrict__ x2, const float* __restrict__ w2,
    float* __restrict__ qdata, float* __restrict__ qidx)
{
    __shared__ float xs[FBM][FBK + FPAD];
    __shared__ float ws[FBN][FBK + FPAD];
    __shared__ float redS[FBM][16];
    __shared__ int   redC[FBM][16];
    __shared__ int   bestC[FBM];

    const int tid = threadIdx.x, tr = tid >> 4, tc = tid & 15;
    const int r0 = blockIdx.x * FBM;
    float best[4]; int bidx[4];
    #pragma unroll
    for (int i = 0; i < 4; ++i) { best[i] = FLT_MAX; bidx[i] = 0x7FFFFFFF; }
    float x2r[4];
    #pragma unroll
    for (int i = 0; i < 4; ++i) x2r[i] = x2[r0 + tr + 16 * i];

    for (int qt = 0; qt < Qn / FBN; ++qt) {
        const int c0 = qt * FBN;
        float acc[4][8];
        #pragma unroll
        for (int i = 0; i < 4; ++i)
            #pragma unroll
            for (int j = 0; j < 8; ++j) acc[i][j] = 0.f;
        for (int kt = 0; kt < E / FBK; ++kt) {
            __syncthreads();
            const int kk = (tid & 15) * 4, rr = tid >> 4;
            #pragma unroll
            for (int m = 0; m < 4; ++m)
                *(float4*)&xs[m * 16 + rr][kk] =
                    *(const float4*)(x + (size_t)(r0 + m * 16 + rr) * E + kt * FBK + kk);
            #pragma unroll
            for (int m = 0; m < 8; ++m)
                *(float4*)&ws[m * 16 + rr][kk] =
                    *(const float4*)(w + (size_t)(c0 + m * 16 + rr) * E + kt * FBK + kk);
            __syncthreads();
            #pragma unroll
            for (int k4 = 0; k4 < FBK / 4; ++k4) {
                float4 a[4], bb[8];
                #pragma unroll
                for (int i = 0; i < 4; ++i) a[i] = *(const float4*)&xs[tr + 16 * i][k4 * 4];
                #pragma unroll
                for (int j = 0; j < 8; ++j) bb[j] = *(const float4*)&ws[tc + 16 * j][k4 * 4];
                #pragma unroll
                for (int i = 0; i < 4; ++i)
                    #pragma unroll
                    for (int j = 0; j < 8; ++j) {
                        acc[i][j] += a[i].x * bb[j].x; acc[i][j] += a[i].y * bb[j].y;
                        acc[i][j] += a[i].z * bb[j].z; acc[i][j] += a[i].w * bb[j].w;
                    }
            }
        }
        #pragma unroll
        for (int i = 0; i < 4; ++i)
            #pragma unroll
            for (int j = 0; j < 8; ++j) {
                int c = c0 + tc + 16 * j;
                float s = (x2r[i] - 2.0f * acc[i][j]) + w2[c];
                if (s < best[i]) { best[i] = s; bidx[i] = c; }
            }
    }
    #pragma unroll
    for (int i = 0; i < 4; ++i) { redS[tr + 16 * i][tc] = best[i]; redC[tr + 16 * i][tc] = bidx[i]; }
    __syncthreads();
    if (tid < FBM) {
        float bs = FLT_MAX; int bc = 0x7FFFFFFF;
        #pragma unroll
        for (int t = 0; t < 16; ++t) {
            float s = redS[tid][t]; int c = redC[tid][t];
            if (s < bs || (s == bs && c < bc)) { bs = s; bc = c; }
        }
        qidx[r0 + tid] = (float)bc; bestC[tid] = bc;
    }
    __syncthreads();
    for (int it = 0; it < FBM / 4; ++it) {
        int row = it * 4 + (tid >> 6), c = bestC[row], kk = (tid & 63) * 4;
        *(float4*)(qdata + (size_t)(r0 + row) * E + kk) = *(const float4*)(w + (size_t)c * E + kk);
    }
}

// ---------------------------------------------------------------------------
extern "C" void kernel_launch(void* const* d_in, const int* in_sizes, int n_in,
                              void* d_out, int out_size, void* d_ws, size_t ws_size,
                              hipStream_t stream) {
    const float* x = (const float*)d_in[0];
    const float* w = (const float*)d_in[1];
    const int N = in_sizes[0] / E;                      // 32768

    float* qdata = (float*)d_out;
    float* qidx  = (float*)d_out + (size_t)N * E;

    size_t off = 0;
    auto carve = [&](size_t bytes) { size_t p = off; off += (bytes + 255) & ~(size_t)255; return p; };
    size_t oA16 = carve((size_t)N  * 256 * sizeof(_Float16));     // 16.8 MB
    size_t oB16 = carve((size_t)Qn * 256 * sizeof(_Float16));     //  2.1 MB
    size_t ow2  = carve((size_t)Qn * sizeof(float));
    size_t oT   = carve((size_t)N * 32 * sizeof(float4));         // 16.8 MB
    size_t ox2f = carve((size_t)N * sizeof(float));               // fallback only

    if (ws_size >= off && (N % 128) == 0) {
        char* ws = (char*)d_ws;
        _Float16* A16 = (_Float16*)(ws + oA16);
        _Float16* B16 = (_Float16*)(ws + oB16);
        float* w2    = (float*)(ws + ow2);
        float4* top4 = (float4*)(ws + oT);

        prep_kernel<<<N / 4 + Qn / 4, 256, 0, stream>>>(x, w, A16, B16, w2, N / 4);
        vq_mfma_kernel<<<dim3(N / 128, Qn / 128), 256, 0, stream>>>(A16, B16, top4);
        finalize_kernel<<<N / 4, 256, 0, stream>>>(top4, x, w, w2, qdata, qidx);
    } else {
        float* x2 = (float*)d_ws;
        float* w2 = x2 + N;
        row_sumsq_kernel<<<N, 64, 0, stream>>>(x, x2);
        row_sumsq_kernel<<<Qn, 64, 0, stream>>>(w, w2);
        vq_fallback_kernel<<<N / FBM, FTH, 0, stream>>>(x, w, x2, w2, qdata, qidx);
    }
}